// Round 1
// baseline (82.945 us; speedup 1.0000x reference)
//
#include <hip/hip_runtime.h>
#include <hip/hip_bf16.h>
#include <cstdint>

#define IDIM 1024
#define HID  256

typedef __attribute__((ext_vector_type(4))) float f32x4;
typedef __attribute__((ext_vector_type(8))) short short8;
typedef __attribute__((ext_vector_type(4))) unsigned int u32x4;

__device__ __forceinline__ unsigned short f2bf(float x) {
  __hip_bfloat16 h = __float2bfloat16(x);
  unsigned short r; __builtin_memcpy(&r, &h, 2); return r;
}
__device__ __forceinline__ unsigned pk_bf16(float a, float b) {
  __hip_bfloat162 h = __float22bfloat162_rn(make_float2(a, b));
  unsigned r; __builtin_memcpy(&r, &h, 4); return r;
}

// ---------------------------------------------------------------------------
// Prep: W1bT[n][k] = bf16(ln_w[k] * W1[k][n])   (transposed, row-scaled)
//       t2[n]  = sum_k ln_w[k]*W1[k][n]
//       tc1[n] = sum_k ln_b[k]*W1[k][n] + b1[n]
// ---------------------------------------------------------------------------
__global__ __launch_bounds__(256)
void prep_kernel(const float* __restrict__ W1, const float* __restrict__ lnw,
                 const float* __restrict__ lnb, const float* __restrict__ b1,
                 unsigned short* __restrict__ w1bt, float* __restrict__ t2g,
                 float* __restrict__ tc1g) {
  const int n = blockIdx.x;
  const int t = threadIdx.x;
  const int k0 = t * 4;
  float s1 = 0.f, s2 = 0.f;
  unsigned short pk[4];
#pragma unroll
  for (int j = 0; j < 4; ++j) {
    const int k = k0 + j;
    const float v  = W1[(size_t)k * HID + n];
    const float sc = lnw[k] * v;
    s2 += sc;
    s1 = fmaf(lnb[k], v, s1);
    pk[j] = f2bf(sc);
  }
  const unsigned lo = (unsigned)pk[0] | ((unsigned)pk[1] << 16);
  const unsigned hi = (unsigned)pk[2] | ((unsigned)pk[3] << 16);
  *reinterpret_cast<uint2*>(w1bt + (size_t)n * IDIM + k0) = make_uint2(lo, hi);
#pragma unroll
  for (int d = 1; d < 64; d <<= 1) { s1 += __shfl_xor(s1, d); s2 += __shfl_xor(s2, d); }
  __shared__ float red[8];
  if ((t & 63) == 0) { red[(t >> 6) * 2] = s1; red[(t >> 6) * 2 + 1] = s2; }
  __syncthreads();
  if (t == 0) {
    tc1g[n] = red[0] + red[2] + red[4] + red[6] + b1[n];
    t2g[n]  = red[1] + red[3] + red[5] + red[7];
  }
}

// ---------------------------------------------------------------------------
// Main fused kernel. One block = 64 rows, full 256 hidden cols.
// z[r,n] = rs_r*acc[r,n] - (mu_r*rs_r)*t2[n] + tc1[n];  h=gelu(z);  out=h@W2+b2
// LDS: A dbuf 2x8KiB | B dbuf 2x32KiB  (=80KiB -> 2 blocks/CU)
// XOR swizzle (16B chunk ^= row&7) on both tiles; B staged with pre-swizzled
// global source through global_load_lds (linear LDS dest).
// ---------------------------------------------------------------------------
__global__ __launch_bounds__(256, 2)
void head_kernel(const float* __restrict__ emb,
                 const unsigned short* __restrict__ w1bt,
                 const float* __restrict__ t2g, const float* __restrict__ tc1g,
                 const float* __restrict__ w2g, const float* __restrict__ b2g,
                 float* __restrict__ out) {
  __shared__ __align__(16) char smem[81920];
  char* const smA = smem;          // [2][64][64] bf16
  char* const smB = smem + 16384;  // [2][256][64] bf16
  float* const stats = reinterpret_cast<float*>(smem);        // overlay (post-loop)
  float* const pout  = reinterpret_cast<float*>(smem + 512);  // overlay (post-loop)

  const int t  = threadIdx.x;
  const int l  = t & 63;
  const int w  = t >> 6;
  const int lr = l & 15;
  const int lk = l >> 4;
  const int m0 = blockIdx.x * 64;

  // A staging: thread owns row ar, cols (t&3)*16..+16 of each K-step
  const int ar  = t >> 2;
  const int acb = (t & 3) * 2;  // first 16B chunk index (of 8 per row)
  const float* const Ag = emb + (size_t)(m0 + ar) * IDIM + (t & 3) * 16;
  char* const aw0 = smA + ar * 128 + ((acb ^ (ar & 7)) * 16);
  char* const aw1 = smA + ar * 128 + (((acb + 1) ^ (ar & 7)) * 16);

  // B staging (global_load_lds): lane's phys slot row/chunk -> pre-swizzled src
  const int brow = w * 64 + (l >> 3);   // + i*8 per instruction
  const int blc  = (l & 7) ^ (l >> 3);  // logical chunk feeding this phys slot

  f32x4 acc[4][4];
#pragma unroll
  for (int i = 0; i < 4; ++i)
#pragma unroll
    for (int j = 0; j < 4; ++j) acc[i][j] = f32x4{0.f, 0.f, 0.f, 0.f};

  float sum = 0.f, ssq = 0.f;
  f32x4 fa0, fa1, fa2, fa3;

  auto issueA = [&](int s) {
    const f32x4* p = reinterpret_cast<const f32x4*>(Ag + s * 64);
    fa0 = p[0]; fa1 = p[1]; fa2 = p[2]; fa3 = p[3];
  };
  auto issueB = [&](int s, int buf) {
#pragma unroll
    for (int i = 0; i < 8; ++i) {
      char* dst = smB + buf * 32768 + (w * 8 + i) * 1024;
      const unsigned short* src =
          w1bt + (size_t)(brow + i * 8) * IDIM + s * 64 + blc * 8;
      __builtin_amdgcn_global_load_lds(
          reinterpret_cast<const __attribute__((address_space(1))) unsigned int*>(
              reinterpret_cast<uintptr_t>(src)),
          reinterpret_cast<__attribute__((address_space(3))) unsigned int*>(
              reinterpret_cast<uintptr_t>(dst)),
          16, 0, 0);
    }
  };
  auto writeA = [&](int buf) {
#pragma unroll
    for (int j = 0; j < 4; ++j) { sum += fa0[j]; ssq = fmaf(fa0[j], fa0[j], ssq); }
#pragma unroll
    for (int j = 0; j < 4; ++j) { sum += fa1[j]; ssq = fmaf(fa1[j], fa1[j], ssq); }
#pragma unroll
    for (int j = 0; j < 4; ++j) { sum += fa2[j]; ssq = fmaf(fa2[j], fa2[j], ssq); }
#pragma unroll
    for (int j = 0; j < 4; ++j) { sum += fa3[j]; ssq = fmaf(fa3[j], fa3[j], ssq); }
    const u32x4 c0 = {pk_bf16(fa0[0], fa0[1]), pk_bf16(fa0[2], fa0[3]),
                      pk_bf16(fa1[0], fa1[1]), pk_bf16(fa1[2], fa1[3])};
    const u32x4 c1 = {pk_bf16(fa2[0], fa2[1]), pk_bf16(fa2[2], fa2[3]),
                      pk_bf16(fa3[0], fa3[1]), pk_bf16(fa3[2], fa3[3])};
    *reinterpret_cast<u32x4*>(aw0 + buf * 8192) = c0;
    *reinterpret_cast<u32x4*>(aw1 + buf * 8192) = c1;
  };
  auto compute = [&](int buf) {
    const char* A = smA + buf * 8192;
    const char* B = smB + buf * 32768;
#pragma unroll
    for (int kk = 0; kk < 2; ++kk) {
      short8 av[4], bv[4];
      const int pc = ((kk * 4 + lk) ^ (lr & 7)) * 16;
#pragma unroll
      for (int mi = 0; mi < 4; ++mi)
        av[mi] = *reinterpret_cast<const short8*>(A + (mi * 16 + lr) * 128 + pc);
#pragma unroll
      for (int ni = 0; ni < 4; ++ni)
        bv[ni] = *reinterpret_cast<const short8*>(B + (w * 64 + ni * 16 + lr) * 128 + pc);
#pragma unroll
      for (int mi = 0; mi < 4; ++mi)
#pragma unroll
        for (int ni = 0; ni < 4; ++ni)
          acc[mi][ni] = __builtin_amdgcn_mfma_f32_16x16x32_bf16(av[mi], bv[ni],
                                                                acc[mi][ni], 0, 0, 0);
    }
  };

  // prologue: stage step 0 into buf 0
  issueA(0);
  issueB(0, 0);
  writeA(0);
  __syncthreads();

  for (int s = 0; s < 16; ++s) {
    const int c = s & 1;
    if (s < 15) { issueA(s + 1); issueB(s + 1, c ^ 1); }
    compute(c);
    if (s < 15) writeA(c ^ 1);
    __syncthreads();  // drains global_load_lds (vmcnt) + ds writes (lgkm)
  }

  // row stats: reduce over the 4 threads sharing a row, publish to LDS overlay
  sum += __shfl_xor(sum, 1); sum += __shfl_xor(sum, 2);
  ssq += __shfl_xor(ssq, 1); ssq += __shfl_xor(ssq, 2);
  if ((t & 3) == 0) {
    const float mu  = sum * (1.f / 1024.f);
    const float var = ssq * (1.f / 1024.f) - mu * mu;
    const float rs  = rsqrtf(var + 1e-5f);
    stats[ar * 2]     = mu * rs;
    stats[ar * 2 + 1] = rs;
  }
  __syncthreads();

  // epilogue: folded-LN affine -> exact GELU -> tiny second GEMM (256 -> 2)
  float po0[16], po1[16];
#pragma unroll
  for (int i = 0; i < 16; ++i) { po0[i] = 0.f; po1[i] = 0.f; }
#pragma unroll
  for (int ni = 0; ni < 4; ++ni) {
    const int n = w * 64 + ni * 16 + lr;
    const float t2n = t2g[n];
    const float tcn = tc1g[n];
    const float w20 = w2g[n * 2];
    const float w21 = w2g[n * 2 + 1];
#pragma unroll
    for (int mi = 0; mi < 4; ++mi) {
#pragma unroll
      for (int j = 0; j < 4; ++j) {
        const int r = mi * 16 + lk * 4 + j;
        const float mrs = stats[r * 2];
        const float rs  = stats[r * 2 + 1];
        const float z  = fmaf(rs, acc[mi][ni][j], fmaf(-mrs, t2n, tcn));
        const float hh = 0.5f * z * (1.f + erff(z * 0.70710678118654752f));
        po0[mi * 4 + j] = fmaf(hh, w20, po0[mi * 4 + j]);
        po1[mi * 4 + j] = fmaf(hh, w21, po1[mi * 4 + j]);
      }
    }
  }
#pragma unroll
  for (int i = 0; i < 16; ++i) {
#pragma unroll
    for (int d = 1; d < 16; d <<= 1) {
      po0[i] += __shfl_xor(po0[i], d);
      po1[i] += __shfl_xor(po1[i], d);
    }
  }
  if (lr == 0) {
#pragma unroll
    for (int mi = 0; mi < 4; ++mi)
#pragma unroll
      for (int j = 0; j < 4; ++j) {
        const int r = mi * 16 + lk * 4 + j;
        pout[(w * 64 + r) * 2 + 0] = po0[mi * 4 + j];
        pout[(w * 64 + r) * 2 + 1] = po1[mi * 4 + j];
      }
  }
  __syncthreads();
  if (t < 128) {
    const int r = t >> 1, o = t & 1;
    const float v = pout[r * 2 + o] + pout[(64 + r) * 2 + o] +
                    pout[(128 + r) * 2 + o] + pout[(192 + r) * 2 + o];
    out[(size_t)(m0 + r) * 2 + o] = v + b2g[o];
  }
}

extern "C" void kernel_launch(void* const* d_in, const int* in_sizes, int n_in,
                              void* d_out, int out_size, void* d_ws, size_t ws_size,
                              hipStream_t stream) {
  const float* emb = (const float*)d_in[0];
  const float* lnw = (const float*)d_in[1];
  const float* lnb = (const float*)d_in[2];
  const float* W1  = (const float*)d_in[3];
  const float* b1  = (const float*)d_in[4];
  const float* W2  = (const float*)d_in[5];
  const float* b2  = (const float*)d_in[6];
  float* out = (float*)d_out;

  unsigned short* w1bt = (unsigned short*)d_ws;                       // 512 KiB
  float* t2g  = (float*)((char*)d_ws + 524288);                       // 1 KiB
  float* tc1g = (float*)((char*)d_ws + 524288 + 1024);                // 1 KiB

  prep_kernel<<<HID, 256, 0, stream>>>(W1, lnw, lnb, b1, w1bt, t2g, tc1g);
  head_kernel<<<65536 / 64, 256, 0, stream>>>(emb, w1bt, t2g, tc1g, W2, b2, out);
}